// Round 7
// baseline (174.439 us; speedup 1.0000x reference)
//
#include <hip/hip_runtime.h>
#include <hip/hip_bf16.h>
#include <math.h>

// Problem constants: B=2, T=2048, C=1024, H=16, D=64
#define BB 2
#define TT 2048
#define HH 16
#define DD 64
#define CC 1024
#define C3 3072

typedef __attribute__((ext_vector_type(8))) short bf16x8;
typedef __attribute__((ext_vector_type(4))) short bf16x4;
typedef __attribute__((ext_vector_type(4))) float f32x4;
typedef __attribute__((ext_vector_type(2))) unsigned int u32x2;

// round-to-nearest-even fp32 -> bf16 bits
__device__ __forceinline__ unsigned short f2bf(float f) {
  union { float f; unsigned u; } v; v.f = f;
  unsigned r = v.u + 0x7fffu + ((v.u >> 16) & 1u);
  return (unsigned short)(r >> 16);
}
// packed 2x fp32 -> bf16x2 (v_cvt_pk_bf16_f32 on gfx950), RNE
__device__ __forceinline__ unsigned pack2bf(float a, float b) {
  __hip_bfloat162 h = __float22bfloat162_rn(make_float2(a, b));
  union { __hip_bfloat162 h; unsigned u; } cv; cv.h = h;
  return cv.u;
}

// async global->LDS 16B copy (dest = wave-uniform base + lane*16)
__device__ __forceinline__ void async_cp16(const void* g, void* l) {
  __builtin_amdgcn_global_load_lds(
      (const __attribute__((address_space(1))) void*)g,
      (__attribute__((address_space(3))) void*)l, 16, 0, 0);
}

// ---------------------------------------------------------------------------
// prep: one launch does x->bf16 cvt + both weight transposes.
// ---------------------------------------------------------------------------
__global__ __launch_bounds__(256)
void prep(const float* __restrict__ x, const float* __restrict__ w_attn,
          const float* __restrict__ w_proj, unsigned short* __restrict__ xb,
          unsigned short* __restrict__ wat, unsigned short* __restrict__ wpt) {
  __shared__ __align__(16) float Ts[64][68];
  const int bx = blockIdx.x, tid = threadIdx.x;
  if (bx < 1024) {
    int i = bx * 256 + tid;
#pragma unroll
    for (int it = 0; it < 4; ++it, i += 262144) {
      const float4 v = ((const float4*)x)[i];
      bf16x4 o = {(short)f2bf(v.x), (short)f2bf(v.y),
                  (short)f2bf(v.z), (short)f2bf(v.w)};
      ((bf16x4*)xb)[i] = o;
    }
    return;
  }
  const float* W;
  unsigned short* WT;
  int Nd, bound, n0, k0;
  float s;
  if (bx < 1792) {
    const int bid = bx - 1024;
    W = w_attn; WT = wat; Nd = 3072; bound = 1024; s = 0.18033688f;  // 0.125*log2e
    n0 = (bid % 48) * 64; k0 = (bid / 48) * 64;
  } else {
    const int bid = bx - 1792;
    W = w_proj; WT = wpt; Nd = 1024; bound = 0; s = 1.0f;
    n0 = (bid % 16) * 64; k0 = (bid / 16) * 64;
  }
  const int rl = tid >> 4, c4 = tid & 15;
#pragma unroll
  for (int it = 0; it < 4; ++it) {
    const int r = it * 16 + rl;
    *(float4*)&Ts[r][c4 * 4] =
        *(const float4*)(W + (size_t)(k0 + r) * Nd + n0 + c4 * 4);
  }
  __syncthreads();
#pragma unroll
  for (int it = 0; it < 4; ++it) {
    const int n = it * 16 + rl;
    const float sc = (n0 + n < bound) ? s : 1.0f;
    bf16x4 o = {(short)f2bf(Ts[c4 * 4 + 0][n] * sc),
                (short)f2bf(Ts[c4 * 4 + 1][n] * sc),
                (short)f2bf(Ts[c4 * 4 + 2][n] * sc),
                (short)f2bf(Ts[c4 * 4 + 3][n] * sc)};
    *(bf16x4*)(WT + (size_t)(n0 + n) * CC + k0 + c4 * 4) = o;
  }
}

// ---------------------------------------------------------------------------
// gemm_qkv: qkv = xb(4096x1024) @ wat(3072x1024)^T.  Tile 128x128, BK=32,
// dbuf LDS (32 KB), grid 24x32 = 768 blocks = 3 blocks/CU.
// bf16 out; cols>=2048 (V) written transposed into vt[(b*16+h)*64+d][t].
// ---------------------------------------------------------------------------
__global__ __launch_bounds__(256, 3)
void gemm_qkv(const unsigned short* __restrict__ A,
              const unsigned short* __restrict__ BT,
              unsigned short* __restrict__ Cb,
              unsigned short* __restrict__ Vout) {
  __shared__ __align__(16) unsigned short As[2 * 128 * 32];  // 16 KB
  __shared__ __align__(16) unsigned short Bs[2 * 128 * 32];  // 16 KB

  const int tid = threadIdx.x;
  const int w = tid >> 6, lane = tid & 63;
  const int l15 = lane & 15, quad = lane >> 4;
  const int wm = w >> 1, wn = w & 1;
  const int row0 = blockIdx.y * 128, col0 = blockIdx.x * 128;

  const int ca0 = tid, ca1 = tid + 256;
  const int ra0 = ca0 >> 2, ka0 = ((ca0 & 3) ^ ((ca0 >> 3) & 3)) * 8;
  const int ra1 = ca1 >> 2, ka1 = ((ca1 & 3) ^ ((ca1 >> 3) & 3)) * 8;
  const unsigned short* gA0 = A + (size_t)(row0 + ra0) * CC + ka0;
  const unsigned short* gA1 = A + (size_t)(row0 + ra1) * CC + ka1;
  const unsigned short* gB0 = BT + (size_t)(col0 + ra0) * CC + ka0;
  const unsigned short* gB1 = BT + (size_t)(col0 + ra1) * CC + ka1;
  const int la0 = tid * 16, la1 = tid * 16 + 4096;

  const int fro = l15 * 64 + 16 * (quad ^ ((l15 >> 1) & 3));

  f32x4 acc[4][4];
#pragma unroll
  for (int i = 0; i < 4; ++i)
#pragma unroll
    for (int j = 0; j < 4; ++j) acc[i][j] = (f32x4){0.f, 0.f, 0.f, 0.f};

  async_cp16(gA0, (char*)As + la0);
  async_cp16(gA1, (char*)As + la1);
  async_cp16(gB0, (char*)Bs + la0);
  async_cp16(gB1, (char*)Bs + la1);

  for (int i = 0; i < 32; ++i) {
    const int cur = i & 1;
    __syncthreads();

    if (i + 1 < 32) {
      const int k1 = (i + 1) * 32;
      const int ab = (cur ^ 1) * 8192;
      async_cp16(gA0 + k1, (char*)As + ab + la0);
      async_cp16(gA1 + k1, (char*)As + ab + la1);
      async_cp16(gB0 + k1, (char*)Bs + ab + la0);
      async_cp16(gB1 + k1, (char*)Bs + ab + la1);
    }

    const char* fA = (const char*)As + cur * 8192 + wm * 4096 + fro;
    const char* fB = (const char*)Bs + cur * 8192 + wn * 4096 + fro;

    bf16x8 af[4], bf[4];
#pragma unroll
    for (int mt = 0; mt < 4; ++mt) af[mt] = *(const bf16x8*)(fA + mt * 1024);
#pragma unroll
    for (int nt = 0; nt < 4; ++nt) bf[nt] = *(const bf16x8*)(fB + nt * 1024);
#pragma unroll
    for (int mt = 0; mt < 4; ++mt)
#pragma unroll
      for (int nt = 0; nt < 4; ++nt)
        acc[mt][nt] = __builtin_amdgcn_mfma_f32_16x16x32_bf16(
            af[mt], bf[nt], acc[mt][nt], 0, 0, 0);
  }

  if (col0 >= 2048) {
#pragma unroll
    for (int mt = 0; mt < 4; ++mt) {
      const int rbase = row0 + wm * 64 + mt * 16 + quad * 4;
      const int bq = rbase >> 11, t0 = rbase & 2047;
#pragma unroll
      for (int nt = 0; nt < 4; ++nt) {
        const int d = col0 + wn * 64 + nt * 16 + l15 - 2048;
        bf16x4 o = {(short)f2bf(acc[mt][nt][0]), (short)f2bf(acc[mt][nt][1]),
                    (short)f2bf(acc[mt][nt][2]), (short)f2bf(acc[mt][nt][3])};
        *(bf16x4*)(Vout + (((size_t)(bq << 10) + d) << 11) + t0) = o;
      }
    }
  } else {
#pragma unroll
    for (int mt = 0; mt < 4; ++mt) {
      const int rbase = row0 + wm * 64 + mt * 16 + quad * 4;
#pragma unroll
      for (int r = 0; r < 4; ++r) {
        unsigned short* cr =
            Cb + (size_t)(rbase + r) * C3 + col0 + wn * 64 + l15;
#pragma unroll
        for (int nt = 0; nt < 4; ++nt) cr[nt * 16] = f2bf(acc[mt][nt][r]);
      }
    }
  }
}

// ---------------------------------------------------------------------------
// gemm_out: out(4096x1024 fp32) = yb(4096x1024) @ wpt(1024x1024)^T.
// ---------------------------------------------------------------------------
__global__ __launch_bounds__(256, 2)
void gemm_out(const unsigned short* __restrict__ A,
              const unsigned short* __restrict__ BT,
              float* __restrict__ Cf) {
  __shared__ __align__(16) unsigned short As[2 * 64 * 64];    // 16 KB
  __shared__ __align__(16) unsigned short Bs[2 * 128 * 64];   // 32 KB

  const int tid = threadIdx.x;
  const int w = tid >> 6, lane = tid & 63;
  const int l15 = lane & 15, quad = lane >> 4;
  const int wm = w >> 1, wn = w & 1;
  const int row0 = blockIdx.y * 64, col0 = blockIdx.x * 128;

  const int ca0 = tid, ca1 = tid + 256;
  const int ra0 = ca0 >> 3, ka0 = ((ca0 & 7) ^ ((ca0 >> 3) & 7)) * 8;
  const int ra1 = ca1 >> 3, ka1 = ((ca1 & 7) ^ ((ca1 >> 3) & 7)) * 8;
  const unsigned short* gA0 = A + (size_t)(row0 + ra0) * CC + ka0;
  const unsigned short* gA1 = A + (size_t)(row0 + ra1) * CC + ka1;
  const unsigned short* gB[4];
  int lb[4];
#pragma unroll
  for (int t = 0; t < 4; ++t) {
    const int c = tid + t * 256;
    const int rb = c >> 3, kb = ((c & 7) ^ ((c >> 3) & 7)) * 8;
    gB[t] = BT + (size_t)(col0 + rb) * CC + kb;
    lb[t] = c * 16;
  }
  const int la0 = tid * 16, la1 = tid * 16 + 4096;

  const int fro = l15 * 128 + ((quad ^ (l15 & 7)) << 4);

  f32x4 acc[2][4];
#pragma unroll
  for (int i = 0; i < 2; ++i)
#pragma unroll
    for (int j = 0; j < 4; ++j) acc[i][j] = (f32x4){0.f, 0.f, 0.f, 0.f};

  async_cp16(gA0, (char*)As + la0);
  async_cp16(gA1, (char*)As + la1);
#pragma unroll
  for (int t = 0; t < 4; ++t) async_cp16(gB[t], (char*)Bs + lb[t]);

  for (int i = 0; i < 16; ++i) {
    const int cur = i & 1;
    __syncthreads();

    if (i + 1 < 16) {
      const int k1 = (i + 1) * 64;
      const int ab = (cur ^ 1) * 8192, bb = (cur ^ 1) * 16384;
      async_cp16(gA0 + k1, (char*)As + ab + la0);
      async_cp16(gA1 + k1, (char*)As + ab + la1);
#pragma unroll
      for (int t = 0; t < 4; ++t) async_cp16(gB[t] + k1, (char*)Bs + bb + lb[t]);
    }

    const char* fA = (const char*)As + cur * 8192 + wm * 4096 + fro;
    const char* fB = (const char*)Bs + cur * 16384 + wn * 8192 + fro;

#pragma unroll
    for (int kh = 0; kh < 2; ++kh) {
      const int xo = kh * 64;
      bf16x8 af[2], bf[4];
#pragma unroll
      for (int mt = 0; mt < 2; ++mt)
        af[mt] = *(const bf16x8*)(fA + mt * 2048 + ((fro + xo) & 127) - (fro & 127));
#pragma unroll
      for (int nt = 0; nt < 4; ++nt)
        bf[nt] = *(const bf16x8*)(fB + nt * 2048 + ((fro + xo) & 127) - (fro & 127));
#pragma unroll
      for (int mt = 0; mt < 2; ++mt)
#pragma unroll
        for (int nt = 0; nt < 4; ++nt)
          acc[mt][nt] = __builtin_amdgcn_mfma_f32_16x16x32_bf16(
              af[mt], bf[nt], acc[mt][nt], 0, 0, 0);
    }
  }

#pragma unroll
  for (int mt = 0; mt < 2; ++mt) {
    const int rbase = row0 + wm * 32 + mt * 16 + quad * 4;
#pragma unroll
    for (int r = 0; r < 4; ++r) {
      float* cr = Cf + (size_t)(rbase + r) * CC + col0 + wn * 64 + l15;
#pragma unroll
      for (int nt = 0; nt < 4; ++nt) cr[nt * 16] = acc[mt][nt][r];
    }
  }
}

// ---------------------------------------------------------------------------
// MFMA flash attention, round-18: CROSS-TILE DEFERRED PV on r6's structure.
// r6 null (half the LDS reads, 0% gain) -> not LDS-BW-bound; the stall is
// the per-tile serial chain, dominated by the Ps ds_write -> lgkm(0) ->
// ds_read roundtrip + PV all inside one tile, convoyed by the barrier.
// Fix: PV of tile j-1 runs during tile j.  At tile j: issue pf-read(j-1)
// first (latency covered by K-reads + S-MFMAs of tile j), PV(j-1)
// interleaves with exp2(j) on the other pipe, THEN write Ps(j).  DS ops of
// one wave execute in order, so single-buffered Ps stays race-free
// (read(j-1) precedes write(j) in program order).  V is TRIPLE-buffered:
// PV(j-1) reads Vb[(j-1)%3] while staging writes Vb[(j+1)%3] (disjoint);
// K stays double-buffered.  LDS 78,336 B -> still 2 blocks/CU (156.7 KB).
// Also: colsum-MFMAs replaced by r3/r4-proven VALU bf16-rounded l-sum +
// epilogue shfl_xor quad-reduce (-2 MFMA/tile, frees regs).
// Everything else r6-verbatim: 512 thr, (wq x kh2) wave split, 512 blocks,
// XCD bh spread, balanced qb pairing, ct-XOR Ps, fixed-max base-2 softmax.
// ---------------------------------------------------------------------------
__global__ __launch_bounds__(512, 4)
void attn_mfma(const unsigned short* __restrict__ qkvb,
               const unsigned short* __restrict__ vt,
               unsigned short* __restrict__ y) {
  const int n = blockIdx.x;
  const int bh = (n & 7) + 8 * ((n >> 3) & 3);  // 4 bh per XCD -> L2-local K/V
  const int m = n >> 5;
  const int qb = (m < 8) ? m : 23 - m;          // co-resident pair balance
  const int b = bh >> 4, h = bh & 15;
  const int tid = threadIdx.x;
  const int w = tid >> 6;
  const int lane = tid & 63;
  const int l15 = lane & 15, quad = lane >> 4;
  const int wq = w >> 1, kh2 = w & 1;

  __shared__ __align__(16) char Kb[2 * 8192];       // 16 KB (dbuf)
  __shared__ __align__(16) char Vb[3 * 8192];       // 24 KB (tri-buf)
  __shared__ __align__(16) char PsArena[8 * 4608];  // 36,864 B; Red alias
  __shared__ float Red2[4][2][16];

  char* psw = PsArena + w * 4608;  // per-wave: 2 q-groups x 2304 B
  const int psrow = l15 * 144;

  const int lr = lane >> 3;
  const int lc = lane & 7;
  const int srcoff = ((lc ^ lr) << 4);
  const char* ksrc = (const char*)qkvb + ((size_t)(b * TT) * C3 + 1024 + h * 64) * 2;
  const char* vsrc = (const char*)vt + ((size_t)(b * HH + h) * DD * TT) * 2;

  const int fro = l15 * 128 + ((quad ^ (l15 & 7)) << 4);
  const int vxor = kh2 << 6;  // key-half select for V fragment reads

  const int nt = 2 * qb + 2;              // 64-key tiles in block
  const int rmin = qb * 128 + wq * 32;    // wave's min q-row
  const int rmax = rmin + 31;             // wave's max q-row
  const int jl = (rmax - kh2 * 32) >> 6;  // wave's last active tile (may be -1)

  // pf read offset (ct-XOR layout, r6-verbatim)
  const int pfoff = ((((quad >> 1) + l15) & 3) << 5) + ((quad & 1) << 4);

  // Q fragments: wave's 32 rows (2 groups of 16), pre-scaled in prep
  const unsigned short* qrow =
      qkvb + (size_t)(b * TT + rmin + l15) * C3 + h * DD;
  bf16x8 qf[2][2];
#pragma unroll
  for (int qg = 0; qg < 2; ++qg)
#pragma unroll
    for (int kh = 0; kh < 2; ++kh)
      qf[qg][kh] = *(const bf16x8*)(qrow + qg * 16 * C3 + kh * 32 + quad * 8);

  f32x4 O[4][2];
  float lsum[2] = {0.f, 0.f};
#pragma unroll
  for (int dt = 0; dt < 4; ++dt)
#pragma unroll
    for (int qg = 0; qg < 2; ++qg) O[dt][qg] = (f32x4){0.f, 0.f, 0.f, 0.f};

  // prologue: stage tile 0 into K buf 0 / V buf 0
  async_cp16(ksrc + (size_t)(w * 8 + lr) * (C3 * 2) + srcoff, Kb + w * 1024);
  async_cp16(vsrc + (size_t)(w * 8 + lr) * (TT * 2) + srcoff, Vb + w * 1024);

  int pend = -1;  // tile whose P is staged in Ps, PV not yet done
  for (int j = 0; j < nt; ++j) {
    __syncthreads();  // tile j staged; LDS reads of prior tiles drained

    if (j + 1 < nt) {
      const int key1 = (j + 1) * 64;
      async_cp16(ksrc + (size_t)(key1 + w * 8 + lr) * (C3 * 2) + srcoff,
                 Kb + ((j + 1) & 1) * 8192 + w * 1024);
      async_cp16(vsrc + (size_t)(w * 8 + lr) * (TT * 2) + key1 * 2 + srcoff,
                 Vb + ((j + 1) % 3) * 8192 + w * 1024);
    }

    const bool act = (j <= jl);
    const bool havep = (pend >= 0);

    // issue pf reads FIRST (latency covered by K-reads + S-MFMAs below);
    // program order guarantees they precede this tile's Ps writes.
    bf16x8 pf0, pf1;
    if (havep) {
      pf0 = *(const bf16x8*)(psw + psrow + pfoff);
      pf1 = *(const bf16x8*)(psw + 2304 + psrow + pfoff);
    }

    // ---- S^T = K Q^T - 12 for tile j ----
    f32x4 S[2][2];
    if (act) {
      const char* Kc = Kb + (j & 1) * 8192;
      const int klo = 64 * j + kh2 * 32;
#pragma unroll
      for (int kt = 0; kt < 2; ++kt) {
        const int ct = kh2 * 2 + kt;
        bf16x8 k0 = *(const bf16x8*)(Kc + ct * 2048 + fro);
        bf16x8 k1 = *(const bf16x8*)(Kc + ct * 2048 + (fro ^ 64));
#pragma unroll
        for (int qg = 0; qg < 2; ++qg) {
          f32x4 z = (f32x4){-12.f, -12.f, -12.f, -12.f};
          z = __builtin_amdgcn_mfma_f32_16x16x32_bf16(k0, qf[qg][0], z, 0, 0, 0);
          z = __builtin_amdgcn_mfma_f32_16x16x32_bf16(k1, qf[qg][1], z, 0, 0, 0);
          S[kt][qg] = z;
        }
      }
      if (klo + 31 > rmin) {  // diagonal overlap: causal mask
#pragma unroll
        for (int kt = 0; kt < 2; ++kt)
#pragma unroll
          for (int qg = 0; qg < 2; ++qg)
#pragma unroll
            for (int r = 0; r < 4; ++r)
              if (klo + kt * 16 + quad * 4 + r > rmin + qg * 16 + l15)
                S[kt][qg][r] = -INFINITY;
      }
    }

    // ---- deferred PV of tile pend (independent of S(j); V from tri-buf) ----
    if (havep) {
      const char* Vp = Vb + (pend % 3) * 8192;
#pragma unroll
      for (int dt = 0; dt < 4; ++dt) {
        bf16x8 vf = *(const bf16x8*)(Vp + dt * 2048 + (fro ^ vxor));
        O[dt][0] = __builtin_amdgcn_mfma_f32_16x16x32_bf16(vf, pf0, O[dt][0], 0, 0, 0);
        O[dt][1] = __builtin_amdgcn_mfma_f32_16x16x32_bf16(vf, pf1, O[dt][1], 0, 0, 0);
      }
      pend = -1;
    }

    // ---- exp2 + pack + VALU l-sum + Ps write for tile j ----
    if (act) {
#pragma unroll
      for (int kt = 0; kt < 2; ++kt)
#pragma unroll
        for (int qg = 0; qg < 2; ++qg) {
          u32x2 d;
          d[0] = pack2bf(__builtin_amdgcn_exp2f(S[kt][qg][0]),
                         __builtin_amdgcn_exp2f(S[kt][qg][1]));
          d[1] = pack2bf(__builtin_amdgcn_exp2f(S[kt][qg][2]),
                         __builtin_amdgcn_exp2f(S[kt][qg][3]));
          // l-sum of the bf16-ROUNDED values (r3/r4-verified numerics)
          lsum[qg] += __uint_as_float(d[0] << 16) +
                      __uint_as_float(d[0] & 0xffff0000u) +
                      __uint_as_float(d[1] << 16) +
                      __uint_as_float(d[1] & 0xffff0000u);
          *(u32x2*)(psw + qg * 2304 + psrow + (((kt + l15) & 3) << 5) + quad * 8) = d;
        }
      pend = j;
    }
  }

  // ---- drain final pending PV (no staging after last barrier: buf intact) ----
  if (pend >= 0) {
    bf16x8 pf0 = *(const bf16x8*)(psw + psrow + pfoff);
    bf16x8 pf1 = *(const bf16x8*)(psw + 2304 + psrow + pfoff);
    const char* Vp = Vb + (pend % 3) * 8192;
#pragma unroll
    for (int dt = 0; dt < 4; ++dt) {
      bf16x8 vf = *(const bf16x8*)(Vp + dt * 2048 + (fro ^ vxor));
      O[dt][0] = __builtin_amdgcn_mfma_f32_16x16x32_bf16(vf, pf0, O[dt][0], 0, 0, 0);
      O[dt][1] = __builtin_amdgcn_mfma_f32_16x16x32_bf16(vf, pf1, O[dt][1], 0, 0, 0);
    }
  }

  // ---- intra-wave l reduce across quads ----
#pragma unroll
  for (int qg = 0; qg < 2; ++qg) {
    lsum[qg] += __shfl_xor(lsum[qg], 16, 64);
    lsum[qg] += __shfl_xor(lsum[qg], 32, 64);
  }

  // ---- pair-reduction over key-halves: w(kh2=0) += w(kh2=1) ----
  const int epoff = l15 * 64 + ((quad ^ (l15 & 3)) << 4);
  __syncthreads();  // all Ps reads done; arena becomes Red
  if (kh2) {
    char* rs = PsArena + wq * 8192;
#pragma unroll
    for (int dt = 0; dt < 4; ++dt)
#pragma unroll
      for (int qg = 0; qg < 2; ++qg)
        *(f32x4*)(rs + (dt * 2 + qg) * 1024 + epoff) = O[dt][qg];
    if (quad == 0) {
#pragma unroll
      for (int qg = 0; qg < 2; ++qg) Red2[wq][qg][l15] = lsum[qg];
    }
  }
  __syncthreads();
  if (!kh2) {
    const char* rs = PsArena + wq * 8192;
#pragma unroll
    for (int dt = 0; dt < 4; ++dt)
#pragma unroll
      for (int qg = 0; qg < 2; ++qg)
        O[dt][qg] += *(const f32x4*)(rs + (dt * 2 + qg) * 1024 + epoff);
    unsigned short* yr =
        y + (size_t)(b * TT + rmin + l15) * CC + h * DD + quad * 4;
#pragma unroll
    for (int qg = 0; qg < 2; ++qg) {
      const float inv = 1.0f / (lsum[qg] + Red2[wq][qg][l15]);
#pragma unroll
      for (int dt = 0; dt < 4; ++dt) {
        bf16x4 o = {(short)f2bf(O[dt][qg][0] * inv),
                    (short)f2bf(O[dt][qg][1] * inv),
                    (short)f2bf(O[dt][qg][2] * inv),
                    (short)f2bf(O[dt][qg][3] * inv)};
        *(bf16x4*)(yr + (size_t)qg * 16 * CC + dt * 16) = o;
      }
    }
  }
}

// ---------------------------------------------------------------------------
extern "C" void kernel_launch(void* const* d_in, const int* in_sizes, int n_in,
                              void* d_out, int out_size, void* d_ws,
                              size_t ws_size, hipStream_t stream) {
  const float* x      = (const float*)d_in[0];
  const float* w_attn = (const float*)d_in[1];
  const float* w_proj = (const float*)d_in[2];
  float* out = (float*)d_out;

  unsigned short* xb   = (unsigned short*)d_ws;
  unsigned short* wat  = xb + (size_t)4096 * 1024;
  unsigned short* wpt  = wat + (size_t)3072 * 1024;
  unsigned short* qkvb = wpt + (size_t)1024 * 1024;
  unsigned short* vt   = qkvb + (size_t)4096 * 3072;
  unsigned short* yb   = vt + (size_t)BB * HH * DD * TT;

  dim3 blk(256);

  prep<<<2048, blk, 0, stream>>>(x, w_attn, w_proj, xb, wat, wpt);

  gemm_qkv<<<dim3(C3 / 128, (BB * TT) / 128), blk, 0, stream>>>(
      xb, wat, qkvb, vt);

  attn_mfma<<<dim3(512, 1, 1), dim3(512), 0, stream>>>(qkvb, vt, yb);

  gemm_out<<<dim3(CC / 128, (BB * TT) / 64), blk, 0, stream>>>(yb, wpt, out);
}

// Round 8
// 169.407 us; speedup vs baseline: 1.0297x; 1.0297x over previous
//
#include <hip/hip_runtime.h>
#include <hip/hip_bf16.h>
#include <math.h>

// Problem constants: B=2, T=2048, C=1024, H=16, D=64
#define BB 2
#define TT 2048
#define HH 16
#define DD 64
#define CC 1024
#define C3 3072

typedef __attribute__((ext_vector_type(8))) short bf16x8;
typedef __attribute__((ext_vector_type(4))) short bf16x4;
typedef __attribute__((ext_vector_type(4))) float f32x4;
typedef __attribute__((ext_vector_type(2))) unsigned int u32x2;

// round-to-nearest-even fp32 -> bf16 bits
__device__ __forceinline__ unsigned short f2bf(float f) {
  union { float f; unsigned u; } v; v.f = f;
  unsigned r = v.u + 0x7fffu + ((v.u >> 16) & 1u);
  return (unsigned short)(r >> 16);
}
// packed 2x fp32 -> bf16x2 (v_cvt_pk_bf16_f32 on gfx950), RNE
__device__ __forceinline__ unsigned pack2bf(float a, float b) {
  __hip_bfloat162 h = __float22bfloat162_rn(make_float2(a, b));
  union { __hip_bfloat162 h; unsigned u; } cv; cv.h = h;
  return cv.u;
}

// async global->LDS 16B copy (dest = wave-uniform base + lane*16)
__device__ __forceinline__ void async_cp16(const void* g, void* l) {
  __builtin_amdgcn_global_load_lds(
      (const __attribute__((address_space(1))) void*)g,
      (__attribute__((address_space(3))) void*)l, 16, 0, 0);
}

// ---------------------------------------------------------------------------
// prep: one launch does x->bf16 cvt + both weight transposes.
// ---------------------------------------------------------------------------
__global__ __launch_bounds__(256)
void prep(const float* __restrict__ x, const float* __restrict__ w_attn,
          const float* __restrict__ w_proj, unsigned short* __restrict__ xb,
          unsigned short* __restrict__ wat, unsigned short* __restrict__ wpt) {
  __shared__ __align__(16) float Ts[64][68];
  const int bx = blockIdx.x, tid = threadIdx.x;
  if (bx < 1024) {
    int i = bx * 256 + tid;
#pragma unroll
    for (int it = 0; it < 4; ++it, i += 262144) {
      const float4 v = ((const float4*)x)[i];
      bf16x4 o = {(short)f2bf(v.x), (short)f2bf(v.y),
                  (short)f2bf(v.z), (short)f2bf(v.w)};
      ((bf16x4*)xb)[i] = o;
    }
    return;
  }
  const float* W;
  unsigned short* WT;
  int Nd, bound, n0, k0;
  float s;
  if (bx < 1792) {
    const int bid = bx - 1024;
    W = w_attn; WT = wat; Nd = 3072; bound = 1024; s = 0.18033688f;  // 0.125*log2e
    n0 = (bid % 48) * 64; k0 = (bid / 48) * 64;
  } else {
    const int bid = bx - 1792;
    W = w_proj; WT = wpt; Nd = 1024; bound = 0; s = 1.0f;
    n0 = (bid % 16) * 64; k0 = (bid / 16) * 64;
  }
  const int rl = tid >> 4, c4 = tid & 15;
#pragma unroll
  for (int it = 0; it < 4; ++it) {
    const int r = it * 16 + rl;
    *(float4*)&Ts[r][c4 * 4] =
        *(const float4*)(W + (size_t)(k0 + r) * Nd + n0 + c4 * 4);
  }
  __syncthreads();
#pragma unroll
  for (int it = 0; it < 4; ++it) {
    const int n = it * 16 + rl;
    const float sc = (n0 + n < bound) ? s : 1.0f;
    bf16x4 o = {(short)f2bf(Ts[c4 * 4 + 0][n] * sc),
                (short)f2bf(Ts[c4 * 4 + 1][n] * sc),
                (short)f2bf(Ts[c4 * 4 + 2][n] * sc),
                (short)f2bf(Ts[c4 * 4 + 3][n] * sc)};
    *(bf16x4*)(WT + (size_t)(n0 + n) * CC + k0 + c4 * 4) = o;
  }
}

// ---------------------------------------------------------------------------
// gemm_qkv: qkv = xb(4096x1024) @ wat(3072x1024)^T.  Tile 128x128, BK=32,
// dbuf LDS (32 KB), grid 24x32 = 768 blocks = 3 blocks/CU.
// bf16 out; cols>=2048 (V) written transposed into vt[(b*16+h)*64+d][t].
// ---------------------------------------------------------------------------
__global__ __launch_bounds__(256, 3)
void gemm_qkv(const unsigned short* __restrict__ A,
              const unsigned short* __restrict__ BT,
              unsigned short* __restrict__ Cb,
              unsigned short* __restrict__ Vout) {
  __shared__ __align__(16) unsigned short As[2 * 128 * 32];  // 16 KB
  __shared__ __align__(16) unsigned short Bs[2 * 128 * 32];  // 16 KB

  const int tid = threadIdx.x;
  const int w = tid >> 6, lane = tid & 63;
  const int l15 = lane & 15, quad = lane >> 4;
  const int wm = w >> 1, wn = w & 1;
  const int row0 = blockIdx.y * 128, col0 = blockIdx.x * 128;

  const int ca0 = tid, ca1 = tid + 256;
  const int ra0 = ca0 >> 2, ka0 = ((ca0 & 3) ^ ((ca0 >> 3) & 3)) * 8;
  const int ra1 = ca1 >> 2, ka1 = ((ca1 & 3) ^ ((ca1 >> 3) & 3)) * 8;
  const unsigned short* gA0 = A + (size_t)(row0 + ra0) * CC + ka0;
  const unsigned short* gA1 = A + (size_t)(row0 + ra1) * CC + ka1;
  const unsigned short* gB0 = BT + (size_t)(col0 + ra0) * CC + ka0;
  const unsigned short* gB1 = BT + (size_t)(col0 + ra1) * CC + ka1;
  const int la0 = tid * 16, la1 = tid * 16 + 4096;

  const int fro = l15 * 64 + 16 * (quad ^ ((l15 >> 1) & 3));

  f32x4 acc[4][4];
#pragma unroll
  for (int i = 0; i < 4; ++i)
#pragma unroll
    for (int j = 0; j < 4; ++j) acc[i][j] = (f32x4){0.f, 0.f, 0.f, 0.f};

  async_cp16(gA0, (char*)As + la0);
  async_cp16(gA1, (char*)As + la1);
  async_cp16(gB0, (char*)Bs + la0);
  async_cp16(gB1, (char*)Bs + la1);

  for (int i = 0; i < 32; ++i) {
    const int cur = i & 1;
    __syncthreads();

    if (i + 1 < 32) {
      const int k1 = (i + 1) * 32;
      const int ab = (cur ^ 1) * 8192;
      async_cp16(gA0 + k1, (char*)As + ab + la0);
      async_cp16(gA1 + k1, (char*)As + ab + la1);
      async_cp16(gB0 + k1, (char*)Bs + ab + la0);
      async_cp16(gB1 + k1, (char*)Bs + ab + la1);
    }

    const char* fA = (const char*)As + cur * 8192 + wm * 4096 + fro;
    const char* fB = (const char*)Bs + cur * 8192 + wn * 4096 + fro;

    bf16x8 af[4], bf[4];
#pragma unroll
    for (int mt = 0; mt < 4; ++mt) af[mt] = *(const bf16x8*)(fA + mt * 1024);
#pragma unroll
    for (int nt = 0; nt < 4; ++nt) bf[nt] = *(const bf16x8*)(fB + nt * 1024);
#pragma unroll
    for (int mt = 0; mt < 4; ++mt)
#pragma unroll
      for (int nt = 0; nt < 4; ++nt)
        acc[mt][nt] = __builtin_amdgcn_mfma_f32_16x16x32_bf16(
            af[mt], bf[nt], acc[mt][nt], 0, 0, 0);
  }

  if (col0 >= 2048) {
#pragma unroll
    for (int mt = 0; mt < 4; ++mt) {
      const int rbase = row0 + wm * 64 + mt * 16 + quad * 4;
      const int bq = rbase >> 11, t0 = rbase & 2047;
#pragma unroll
      for (int nt = 0; nt < 4; ++nt) {
        const int d = col0 + wn * 64 + nt * 16 + l15 - 2048;
        bf16x4 o = {(short)f2bf(acc[mt][nt][0]), (short)f2bf(acc[mt][nt][1]),
                    (short)f2bf(acc[mt][nt][2]), (short)f2bf(acc[mt][nt][3])};
        *(bf16x4*)(Vout + (((size_t)(bq << 10) + d) << 11) + t0) = o;
      }
    }
  } else {
#pragma unroll
    for (int mt = 0; mt < 4; ++mt) {
      const int rbase = row0 + wm * 64 + mt * 16 + quad * 4;
#pragma unroll
      for (int r = 0; r < 4; ++r) {
        unsigned short* cr =
            Cb + (size_t)(rbase + r) * C3 + col0 + wn * 64 + l15;
#pragma unroll
        for (int nt = 0; nt < 4; ++nt) cr[nt * 16] = f2bf(acc[mt][nt][r]);
      }
    }
  }
}

// ---------------------------------------------------------------------------
// gemm_out: out(4096x1024 fp32) = yb(4096x1024) @ wpt(1024x1024)^T.
// ---------------------------------------------------------------------------
__global__ __launch_bounds__(256, 2)
void gemm_out(const unsigned short* __restrict__ A,
              const unsigned short* __restrict__ BT,
              float* __restrict__ Cf) {
  __shared__ __align__(16) unsigned short As[2 * 64 * 64];    // 16 KB
  __shared__ __align__(16) unsigned short Bs[2 * 128 * 64];   // 32 KB

  const int tid = threadIdx.x;
  const int w = tid >> 6, lane = tid & 63;
  const int l15 = lane & 15, quad = lane >> 4;
  const int wm = w >> 1, wn = w & 1;
  const int row0 = blockIdx.y * 64, col0 = blockIdx.x * 128;

  const int ca0 = tid, ca1 = tid + 256;
  const int ra0 = ca0 >> 3, ka0 = ((ca0 & 7) ^ ((ca0 >> 3) & 7)) * 8;
  const int ra1 = ca1 >> 3, ka1 = ((ca1 & 7) ^ ((ca1 >> 3) & 7)) * 8;
  const unsigned short* gA0 = A + (size_t)(row0 + ra0) * CC + ka0;
  const unsigned short* gA1 = A + (size_t)(row0 + ra1) * CC + ka1;
  const unsigned short* gB[4];
  int lb[4];
#pragma unroll
  for (int t = 0; t < 4; ++t) {
    const int c = tid + t * 256;
    const int rb = c >> 3, kb = ((c & 7) ^ ((c >> 3) & 7)) * 8;
    gB[t] = BT + (size_t)(col0 + rb) * CC + kb;
    lb[t] = c * 16;
  }
  const int la0 = tid * 16, la1 = tid * 16 + 4096;

  const int fro = l15 * 128 + ((quad ^ (l15 & 7)) << 4);

  f32x4 acc[2][4];
#pragma unroll
  for (int i = 0; i < 2; ++i)
#pragma unroll
    for (int j = 0; j < 4; ++j) acc[i][j] = (f32x4){0.f, 0.f, 0.f, 0.f};

  async_cp16(gA0, (char*)As + la0);
  async_cp16(gA1, (char*)As + la1);
#pragma unroll
  for (int t = 0; t < 4; ++t) async_cp16(gB[t], (char*)Bs + lb[t]);

  for (int i = 0; i < 16; ++i) {
    const int cur = i & 1;
    __syncthreads();

    if (i + 1 < 16) {
      const int k1 = (i + 1) * 64;
      const int ab = (cur ^ 1) * 8192, bb = (cur ^ 1) * 16384;
      async_cp16(gA0 + k1, (char*)As + ab + la0);
      async_cp16(gA1 + k1, (char*)As + ab + la1);
#pragma unroll
      for (int t = 0; t < 4; ++t) async_cp16(gB[t] + k1, (char*)Bs + bb + lb[t]);
    }

    const char* fA = (const char*)As + cur * 8192 + wm * 4096 + fro;
    const char* fB = (const char*)Bs + cur * 16384 + wn * 8192 + fro;

#pragma unroll
    for (int kh = 0; kh < 2; ++kh) {
      const int xo = kh * 64;
      bf16x8 af[2], bf[4];
#pragma unroll
      for (int mt = 0; mt < 2; ++mt)
        af[mt] = *(const bf16x8*)(fA + mt * 2048 + ((fro + xo) & 127) - (fro & 127));
#pragma unroll
      for (int nt = 0; nt < 4; ++nt)
        bf[nt] = *(const bf16x8*)(fB + nt * 2048 + ((fro + xo) & 127) - (fro & 127));
#pragma unroll
      for (int mt = 0; mt < 2; ++mt)
#pragma unroll
        for (int nt = 0; nt < 4; ++nt)
          acc[mt][nt] = __builtin_amdgcn_mfma_f32_16x16x32_bf16(
              af[mt], bf[nt], acc[mt][nt], 0, 0, 0);
    }
  }

#pragma unroll
  for (int mt = 0; mt < 2; ++mt) {
    const int rbase = row0 + wm * 32 + mt * 16 + quad * 4;
#pragma unroll
    for (int r = 0; r < 4; ++r) {
      float* cr = Cf + (size_t)(rbase + r) * CC + col0 + wn * 64 + l15;
#pragma unroll
      for (int nt = 0; nt < 4; ++nt) cr[nt * 16] = acc[mt][nt][r];
    }
  }
}

// ---------------------------------------------------------------------------
// MFMA flash attention, round-19: UNIFORM BLOCK DURATIONS.
// r5/r6/r7 all pinned at ~43.5us with Occupancy ~23%: block durations were
// 2..32 tiles; after the short co-resident partner finished, the qb=15
// straggler ran ~30 tiles SOLO at 2 waves/SIMD -> makespan 30x3550cyc ~ 44us
// = the plateau.  Fix (r0's trick at 8 waves): every block runs TWO 64-row
// q-tile phases {31-qp, qp} -> exactly 33 tiles each; all 512 blocks are
// identical, 2 blocks/CU co-resident for the WHOLE kernel (16 waves/CU,
// 4/SIMD), and the two blocks' barriers interleave.
// Per phase: 8 waves = (wq: 16 q-rows) x (kh2: 32-key half) — the r6-proven
// hybrid scaled down; kh2-pair epilogue reduction per phase (r6's epoff).
// All else verbatim: staging (2 cp16/wave), ct-XOR Ps (kt slots), fixed-max
// base-2 softmax, VALU bf16-rounded l-sum + shfl_xor, XCD bh spread.
// LDS 51.5 KB.
// ---------------------------------------------------------------------------
__global__ __launch_bounds__(512, 4)
void attn_mfma(const unsigned short* __restrict__ qkvb,
               const unsigned short* __restrict__ vt,
               unsigned short* __restrict__ y) {
  const int n = blockIdx.x;
  const int bh = (n & 7) + 8 * ((n >> 3) & 3);  // 4 bh per XCD -> L2-local K/V
  const int qp = n >> 5;                        // 0..15
  const int b = bh >> 4, h = bh & 15;
  const int tid = threadIdx.x;
  const int w = tid >> 6;
  const int lane = tid & 63;
  const int l15 = lane & 15, quad = lane >> 4;
  const int wq = w >> 1, kh2 = w & 1;

  __shared__ __align__(16) char Kb[2 * 8192];       // 16 KB (dbuf)
  __shared__ __align__(16) char Vb[2 * 8192];       // 16 KB (dbuf)
  __shared__ __align__(16) char PsArena[8 * 2304];  // 18,432 B; Red alias
  __shared__ float Red2[4][16];

  char* psw = PsArena + w * 2304;  // per-wave private P staging (ct-XOR swz)
  const int psrow = l15 * 144;

  const int lr = lane >> 3;
  const int lc = lane & 7;
  const int srcoff = ((lc ^ lr) << 4);
  const char* ksrc = (const char*)qkvb + ((size_t)(b * TT) * C3 + 1024 + h * 64) * 2;
  const char* vsrc = (const char*)vt + ((size_t)(b * HH + h) * DD * TT) * 2;

  const int fro = l15 * 128 + ((quad ^ (l15 & 7)) << 4);
  const int vxor = kh2 << 6;  // key-half select for V fragment reads
  const int pfoff = ((((quad >> 1) + l15) & 3) << 5) + ((quad & 1) << 4);
  const int epoff = l15 * 64 + ((quad ^ (l15 & 3)) << 4);

  for (int phase = 0; phase < 2; ++phase) {
    const int qt = phase ? qp : 31 - qp;   // phase tiles: (32-qp)+(qp+1)=33
    const int nt = qt + 1;                 // 64-key tiles this phase
    const int rmin = qt * 64 + wq * 16;    // wave's min q-row
    const int rmax = rmin + 15;
    const int dk = rmax - kh2 * 32;
    const int jl = (dk >= 0) ? (dk >> 6) : -1;  // wave's last active tile

    if (phase) __syncthreads();  // phase-0 LDS reads fully drained

    // Q fragments: wave's 16 rows (pre-scaled by 0.125*log2e in prep)
    const unsigned short* qrow =
        qkvb + (size_t)(b * TT + rmin + l15) * C3 + h * DD;
    bf16x8 qf0 = *(const bf16x8*)(qrow + quad * 8);
    bf16x8 qf1 = *(const bf16x8*)(qrow + 32 + quad * 8);

    f32x4 O[4];
    float lsum = 0.f;
#pragma unroll
    for (int dt = 0; dt < 4; ++dt) O[dt] = (f32x4){0.f, 0.f, 0.f, 0.f};

    // prologue: stage tile 0 into buf 0 (each wave: 8 K-rows + 8 V-rows)
    async_cp16(ksrc + (size_t)(w * 8 + lr) * (C3 * 2) + srcoff, Kb + w * 1024);
    async_cp16(vsrc + (size_t)(w * 8 + lr) * (TT * 2) + srcoff, Vb + w * 1024);

    for (int j = 0; j < nt; ++j) {
      const int cur = j & 1;
      __syncthreads();  // tile j staged; reads of buf cur^1 done

      if (j + 1 < nt) {
        const int key1 = (j + 1) * 64;
        async_cp16(ksrc + (size_t)(key1 + w * 8 + lr) * (C3 * 2) + srcoff,
                   Kb + (cur ^ 1) * 8192 + w * 1024);
        async_cp16(vsrc + (size_t)(w * 8 + lr) * (TT * 2) + key1 * 2 + srcoff,
                   Vb + (cur ^ 1) * 8192 + w * 1024);
      }

      if (j > jl) continue;  // inactive tile: staging + barrier only

      const char* Kc = Kb + cur * 8192;
      const char* Vc = Vb + cur * 8192;
      const int klo = 64 * j + kh2 * 32;  // wave's first key this tile

      // ---- S^T = K Q^T - 12 (32 keys x 16 queries) ----
      f32x4 S[2];
#pragma unroll
      for (int kt = 0; kt < 2; ++kt) {
        const int ct = kh2 * 2 + kt;
        bf16x8 k0 = *(const bf16x8*)(Kc + ct * 2048 + fro);
        bf16x8 k1 = *(const bf16x8*)(Kc + ct * 2048 + (fro ^ 64));
        f32x4 z = (f32x4){-12.f, -12.f, -12.f, -12.f};
        z = __builtin_amdgcn_mfma_f32_16x16x32_bf16(k0, qf0, z, 0, 0, 0);
        z = __builtin_amdgcn_mfma_f32_16x16x32_bf16(k1, qf1, z, 0, 0, 0);
        S[kt] = z;
      }

      if (klo + 31 > rmin) {  // diagonal overlap: causal mask
#pragma unroll
        for (int kt = 0; kt < 2; ++kt)
#pragma unroll
          for (int r = 0; r < 4; ++r)
            if (klo + kt * 16 + quad * 4 + r > rmin + l15)
              S[kt][r] = -INFINITY;
      }

      // ---- P^T = exp2(S^T); pack + VALU l-sum -> swizzled Ps ----
#pragma unroll
      for (int kt = 0; kt < 2; ++kt) {
        u32x2 d;
        d[0] = pack2bf(__builtin_amdgcn_exp2f(S[kt][0]),
                       __builtin_amdgcn_exp2f(S[kt][1]));
        d[1] = pack2bf(__builtin_amdgcn_exp2f(S[kt][2]),
                       __builtin_amdgcn_exp2f(S[kt][3]));
        // l-sum of the bf16-ROUNDED values (r3/r4-verified numerics)
        lsum += __uint_as_float(d[0] << 16) +
                __uint_as_float(d[0] & 0xffff0000u) +
                __uint_as_float(d[1] << 16) +
                __uint_as_float(d[1] & 0xffff0000u);
        *(u32x2*)(psw + psrow + (((kt + l15) & 3) << 5) + quad * 8) = d;
      }

      // ---- pf read + PV (O^T += V^T P^T) ----
      const bf16x8 pf = *(const bf16x8*)(psw + psrow + pfoff);
#pragma unroll
      for (int dt = 0; dt < 4; ++dt) {
        bf16x8 vf = *(const bf16x8*)(Vc + dt * 2048 + (fro ^ vxor));
        O[dt] = __builtin_amdgcn_mfma_f32_16x16x32_bf16(vf, pf, O[dt], 0, 0, 0);
      }
    }

    // ---- intra-wave l reduce across quads ----
    lsum += __shfl_xor(lsum, 16, 64);
    lsum += __shfl_xor(lsum, 32, 64);

    // ---- pair-reduction over key-halves: w(kh2=0) += w(kh2=1) ----
    __syncthreads();  // all Ps/K/V reads done; arena becomes Red
    if (kh2) {
      char* rs = PsArena + wq * 4096;
#pragma unroll
      for (int dt = 0; dt < 4; ++dt)
        *(f32x4*)(rs + dt * 1024 + epoff) = O[dt];
      if (quad == 0) Red2[wq][l15] = lsum;
    }
    __syncthreads();
    if (!kh2) {
      const char* rs = PsArena + wq * 4096;
#pragma unroll
      for (int dt = 0; dt < 4; ++dt)
        O[dt] += *(const f32x4*)(rs + dt * 1024 + epoff);
      const float inv = 1.0f / (lsum + Red2[wq][l15]);
      unsigned short* yr =
          y + (size_t)(b * TT + rmin + l15) * CC + h * DD + quad * 4;
#pragma unroll
      for (int dt = 0; dt < 4; ++dt) {
        bf16x4 o = {(short)f2bf(O[dt][0] * inv), (short)f2bf(O[dt][1] * inv),
                    (short)f2bf(O[dt][2] * inv), (short)f2bf(O[dt][3] * inv)};
        *(bf16x4*)(yr + dt * 16) = o;
      }
    }
  }
}

// ---------------------------------------------------------------------------
extern "C" void kernel_launch(void* const* d_in, const int* in_sizes, int n_in,
                              void* d_out, int out_size, void* d_ws,
                              size_t ws_size, hipStream_t stream) {
  const float* x      = (const float*)d_in[0];
  const float* w_attn = (const float*)d_in[1];
  const float* w_proj = (const float*)d_in[2];
  float* out = (float*)d_out;

  unsigned short* xb   = (unsigned short*)d_ws;
  unsigned short* wat  = xb + (size_t)4096 * 1024;
  unsigned short* wpt  = wat + (size_t)3072 * 1024;
  unsigned short* qkvb = wpt + (size_t)1024 * 1024;
  unsigned short* vt   = qkvb + (size_t)4096 * 3072;
  unsigned short* yb   = vt + (size_t)BB * HH * DD * TT;

  dim3 blk(256);

  prep<<<2048, blk, 0, stream>>>(x, w_attn, w_proj, xb, wat, wpt);

  gemm_qkv<<<dim3(C3 / 128, (BB * TT) / 128), blk, 0, stream>>>(
      xb, wat, qkvb, vt);

  attn_mfma<<<dim3(512, 1, 1), dim3(512), 0, stream>>>(qkvb, vt, yb);

  gemm_out<<<dim3(CC / 128, (BB * TT) / 64), blk, 0, stream>>>(yb, wpt, out);
}

// Round 9
// 169.327 us; speedup vs baseline: 1.0302x; 1.0005x over previous
//
#include <hip/hip_runtime.h>
#include <hip/hip_bf16.h>
#include <math.h>

// Problem constants: B=2, T=2048, C=1024, H=16, D=64
#define BB 2
#define TT 2048
#define HH 16
#define DD 64
#define CC 1024
#define C3 3072

typedef __attribute__((ext_vector_type(8))) short bf16x8;
typedef __attribute__((ext_vector_type(4))) short bf16x4;
typedef __attribute__((ext_vector_type(4))) float f32x4;
typedef __attribute__((ext_vector_type(2))) unsigned int u32x2;

// round-to-nearest-even fp32 -> bf16 bits
__device__ __forceinline__ unsigned short f2bf(float f) {
  union { float f; unsigned u; } v; v.f = f;
  unsigned r = v.u + 0x7fffu + ((v.u >> 16) & 1u);
  return (unsigned short)(r >> 16);
}
// packed 2x fp32 -> bf16x2 (v_cvt_pk_bf16_f32 on gfx950), RNE
__device__ __forceinline__ unsigned pack2bf(float a, float b) {
  __hip_bfloat162 h = __float22bfloat162_rn(make_float2(a, b));
  union { __hip_bfloat162 h; unsigned u; } cv; cv.h = h;
  return cv.u;
}

// async global->LDS 16B copy (dest = wave-uniform base + lane*16)
__device__ __forceinline__ void async_cp16(const void* g, void* l) {
  __builtin_amdgcn_global_load_lds(
      (const __attribute__((address_space(1))) void*)g,
      (__attribute__((address_space(3))) void*)l, 16, 0, 0);
}

// ---------------------------------------------------------------------------
// prep: one launch does x->bf16 cvt + both weight transposes.
// ---------------------------------------------------------------------------
__global__ __launch_bounds__(256)
void prep(const float* __restrict__ x, const float* __restrict__ w_attn,
          const float* __restrict__ w_proj, unsigned short* __restrict__ xb,
          unsigned short* __restrict__ wat, unsigned short* __restrict__ wpt) {
  __shared__ __align__(16) float Ts[64][68];
  const int bx = blockIdx.x, tid = threadIdx.x;
  if (bx < 1024) {
    int i = bx * 256 + tid;
#pragma unroll
    for (int it = 0; it < 4; ++it, i += 262144) {
      const float4 v = ((const float4*)x)[i];
      bf16x4 o = {(short)f2bf(v.x), (short)f2bf(v.y),
                  (short)f2bf(v.z), (short)f2bf(v.w)};
      ((bf16x4*)xb)[i] = o;
    }
    return;
  }
  const float* W;
  unsigned short* WT;
  int Nd, bound, n0, k0;
  float s;
  if (bx < 1792) {
    const int bid = bx - 1024;
    W = w_attn; WT = wat; Nd = 3072; bound = 1024; s = 0.18033688f;  // 0.125*log2e
    n0 = (bid % 48) * 64; k0 = (bid / 48) * 64;
  } else {
    const int bid = bx - 1792;
    W = w_proj; WT = wpt; Nd = 1024; bound = 0; s = 1.0f;
    n0 = (bid % 16) * 64; k0 = (bid / 16) * 64;
  }
  const int rl = tid >> 4, c4 = tid & 15;
#pragma unroll
  for (int it = 0; it < 4; ++it) {
    const int r = it * 16 + rl;
    *(float4*)&Ts[r][c4 * 4] =
        *(const float4*)(W + (size_t)(k0 + r) * Nd + n0 + c4 * 4);
  }
  __syncthreads();
#pragma unroll
  for (int it = 0; it < 4; ++it) {
    const int n = it * 16 + rl;
    const float sc = (n0 + n < bound) ? s : 1.0f;
    bf16x4 o = {(short)f2bf(Ts[c4 * 4 + 0][n] * sc),
                (short)f2bf(Ts[c4 * 4 + 1][n] * sc),
                (short)f2bf(Ts[c4 * 4 + 2][n] * sc),
                (short)f2bf(Ts[c4 * 4 + 3][n] * sc)};
    *(bf16x4*)(WT + (size_t)(n0 + n) * CC + k0 + c4 * 4) = o;
  }
}

// ---------------------------------------------------------------------------
// gemm_qkv: qkv = xb(4096x1024) @ wat(3072x1024)^T.  Tile 128x128, BK=32,
// dbuf LDS (32 KB), grid 24x32 = 768 blocks = 3 blocks/CU.
// bf16 out; cols>=2048 (V) written transposed into vt[(b*16+h)*64+d][t].
// ---------------------------------------------------------------------------
__global__ __launch_bounds__(256, 3)
void gemm_qkv(const unsigned short* __restrict__ A,
              const unsigned short* __restrict__ BT,
              unsigned short* __restrict__ Cb,
              unsigned short* __restrict__ Vout) {
  __shared__ __align__(16) unsigned short As[2 * 128 * 32];  // 16 KB
  __shared__ __align__(16) unsigned short Bs[2 * 128 * 32];  // 16 KB

  const int tid = threadIdx.x;
  const int w = tid >> 6, lane = tid & 63;
  const int l15 = lane & 15, quad = lane >> 4;
  const int wm = w >> 1, wn = w & 1;
  const int row0 = blockIdx.y * 128, col0 = blockIdx.x * 128;

  const int ca0 = tid, ca1 = tid + 256;
  const int ra0 = ca0 >> 2, ka0 = ((ca0 & 3) ^ ((ca0 >> 3) & 3)) * 8;
  const int ra1 = ca1 >> 2, ka1 = ((ca1 & 3) ^ ((ca1 >> 3) & 3)) * 8;
  const unsigned short* gA0 = A + (size_t)(row0 + ra0) * CC + ka0;
  const unsigned short* gA1 = A + (size_t)(row0 + ra1) * CC + ka1;
  const unsigned short* gB0 = BT + (size_t)(col0 + ra0) * CC + ka0;
  const unsigned short* gB1 = BT + (size_t)(col0 + ra1) * CC + ka1;
  const int la0 = tid * 16, la1 = tid * 16 + 4096;

  const int fro = l15 * 64 + 16 * (quad ^ ((l15 >> 1) & 3));

  f32x4 acc[4][4];
#pragma unroll
  for (int i = 0; i < 4; ++i)
#pragma unroll
    for (int j = 0; j < 4; ++j) acc[i][j] = (f32x4){0.f, 0.f, 0.f, 0.f};

  async_cp16(gA0, (char*)As + la0);
  async_cp16(gA1, (char*)As + la1);
  async_cp16(gB0, (char*)Bs + la0);
  async_cp16(gB1, (char*)Bs + la1);

  for (int i = 0; i < 32; ++i) {
    const int cur = i & 1;
    __syncthreads();

    if (i + 1 < 32) {
      const int k1 = (i + 1) * 32;
      const int ab = (cur ^ 1) * 8192;
      async_cp16(gA0 + k1, (char*)As + ab + la0);
      async_cp16(gA1 + k1, (char*)As + ab + la1);
      async_cp16(gB0 + k1, (char*)Bs + ab + la0);
      async_cp16(gB1 + k1, (char*)Bs + ab + la1);
    }

    const char* fA = (const char*)As + cur * 8192 + wm * 4096 + fro;
    const char* fB = (const char*)Bs + cur * 8192 + wn * 4096 + fro;

    bf16x8 af[4], bf[4];
#pragma unroll
    for (int mt = 0; mt < 4; ++mt) af[mt] = *(const bf16x8*)(fA + mt * 1024);
#pragma unroll
    for (int nt = 0; nt < 4; ++nt) bf[nt] = *(const bf16x8*)(fB + nt * 1024);
#pragma unroll
    for (int mt = 0; mt < 4; ++mt)
#pragma unroll
      for (int nt = 0; nt < 4; ++nt)
        acc[mt][nt] = __builtin_amdgcn_mfma_f32_16x16x32_bf16(
            af[mt], bf[nt], acc[mt][nt], 0, 0, 0);
  }

  if (col0 >= 2048) {
#pragma unroll
    for (int mt = 0; mt < 4; ++mt) {
      const int rbase = row0 + wm * 64 + mt * 16 + quad * 4;
      const int bq = rbase >> 11, t0 = rbase & 2047;
#pragma unroll
      for (int nt = 0; nt < 4; ++nt) {
        const int d = col0 + wn * 64 + nt * 16 + l15 - 2048;
        bf16x4 o = {(short)f2bf(acc[mt][nt][0]), (short)f2bf(acc[mt][nt][1]),
                    (short)f2bf(acc[mt][nt][2]), (short)f2bf(acc[mt][nt][3])};
        *(bf16x4*)(Vout + (((size_t)(bq << 10) + d) << 11) + t0) = o;
      }
    }
  } else {
#pragma unroll
    for (int mt = 0; mt < 4; ++mt) {
      const int rbase = row0 + wm * 64 + mt * 16 + quad * 4;
#pragma unroll
      for (int r = 0; r < 4; ++r) {
        unsigned short* cr =
            Cb + (size_t)(rbase + r) * C3 + col0 + wn * 64 + l15;
#pragma unroll
        for (int nt = 0; nt < 4; ++nt) cr[nt * 16] = f2bf(acc[mt][nt][r]);
      }
    }
  }
}

// ---------------------------------------------------------------------------
// gemm_out: out(4096x1024 fp32) = yb(4096x1024) @ wpt(1024x1024)^T.
// ---------------------------------------------------------------------------
__global__ __launch_bounds__(256, 2)
void gemm_out(const unsigned short* __restrict__ A,
              const unsigned short* __restrict__ BT,
              float* __restrict__ Cf) {
  __shared__ __align__(16) unsigned short As[2 * 64 * 64];    // 16 KB
  __shared__ __align__(16) unsigned short Bs[2 * 128 * 64];   // 32 KB

  const int tid = threadIdx.x;
  const int w = tid >> 6, lane = tid & 63;
  const int l15 = lane & 15, quad = lane >> 4;
  const int wm = w >> 1, wn = w & 1;
  const int row0 = blockIdx.y * 64, col0 = blockIdx.x * 128;

  const int ca0 = tid, ca1 = tid + 256;
  const int ra0 = ca0 >> 3, ka0 = ((ca0 & 7) ^ ((ca0 >> 3) & 7)) * 8;
  const int ra1 = ca1 >> 3, ka1 = ((ca1 & 7) ^ ((ca1 >> 3) & 7)) * 8;
  const unsigned short* gA0 = A + (size_t)(row0 + ra0) * CC + ka0;
  const unsigned short* gA1 = A + (size_t)(row0 + ra1) * CC + ka1;
  const unsigned short* gB[4];
  int lb[4];
#pragma unroll
  for (int t = 0; t < 4; ++t) {
    const int c = tid + t * 256;
    const int rb = c >> 3, kb = ((c & 7) ^ ((c >> 3) & 7)) * 8;
    gB[t] = BT + (size_t)(col0 + rb) * CC + kb;
    lb[t] = c * 16;
  }
  const int la0 = tid * 16, la1 = tid * 16 + 4096;

  const int fro = l15 * 128 + ((quad ^ (l15 & 7)) << 4);

  f32x4 acc[2][4];
#pragma unroll
  for (int i = 0; i < 2; ++i)
#pragma unroll
    for (int j = 0; j < 4; ++j) acc[i][j] = (f32x4){0.f, 0.f, 0.f, 0.f};

  async_cp16(gA0, (char*)As + la0);
  async_cp16(gA1, (char*)As + la1);
#pragma unroll
  for (int t = 0; t < 4; ++t) async_cp16(gB[t], (char*)Bs + lb[t]);

  for (int i = 0; i < 16; ++i) {
    const int cur = i & 1;
    __syncthreads();

    if (i + 1 < 16) {
      const int k1 = (i + 1) * 64;
      const int ab = (cur ^ 1) * 8192, bb = (cur ^ 1) * 16384;
      async_cp16(gA0 + k1, (char*)As + ab + la0);
      async_cp16(gA1 + k1, (char*)As + ab + la1);
#pragma unroll
      for (int t = 0; t < 4; ++t) async_cp16(gB[t] + k1, (char*)Bs + bb + lb[t]);
    }

    const char* fA = (const char*)As + cur * 8192 + wm * 4096 + fro;
    const char* fB = (const char*)Bs + cur * 16384 + wn * 8192 + fro;

#pragma unroll
    for (int kh = 0; kh < 2; ++kh) {
      const int xo = kh * 64;
      bf16x8 af[2], bf[4];
#pragma unroll
      for (int mt = 0; mt < 2; ++mt)
        af[mt] = *(const bf16x8*)(fA + mt * 2048 + ((fro + xo) & 127) - (fro & 127));
#pragma unroll
      for (int nt = 0; nt < 4; ++nt)
        bf[nt] = *(const bf16x8*)(fB + nt * 2048 + ((fro + xo) & 127) - (fro & 127));
#pragma unroll
      for (int mt = 0; mt < 2; ++mt)
#pragma unroll
        for (int nt = 0; nt < 4; ++nt)
          acc[mt][nt] = __builtin_amdgcn_mfma_f32_16x16x32_bf16(
              af[mt], bf[nt], acc[mt][nt], 0, 0, 0);
    }
  }

#pragma unroll
  for (int mt = 0; mt < 2; ++mt) {
    const int rbase = row0 + wm * 32 + mt * 16 + quad * 4;
#pragma unroll
    for (int r = 0; r < 4; ++r) {
      float* cr = Cf + (size_t)(rbase + r) * CC + col0 + wn * 64 + l15;
#pragma unroll
      for (int nt = 0; nt < 4; ++nt) cr[nt * 16] = acc[mt][nt][r];
    }
  }
}

// ---------------------------------------------------------------------------
// MFMA flash attention, round-20: r8 uniform-duration structure + CROSS-TILE
// DEFERRED PV.  r8 fixed the straggler makespan (attn <43us, occupancy-true
// 2 blocks/CU co-resident throughout); that makes the per-tile serial chain
// the critical path for the first time -- so r7's deferral technique (null
// under the straggler regime) is re-tested here where it can pay:
//  * at tile j: pf-read(j-1) issued FIRST (latency hides under K ds_reads +
//    S-MFMAs of tile j); PV(j-1) runs under s_setprio(1), overlapping
//    exp2(j) on the VALU pipe; Ps(j) written last.  The Ps write->read
//    roundtrip now spans a barrier + S-phase instead of ~0.
//  * V TRIPLE-buffered (stage (j+1)%3, PV reads pend%3 -- disjoint mod 3);
//    K stays double-buffered.  LDS 59.6 KB -> still 2 blocks/CU.
//  * same-wave DS ordering keeps single-buffer Ps race-free; phase-top and
//    epilogue barriers (r8-verified) cover all cross-wave hazards.
// Everything else r8-verbatim: 512 thr, (wq x kh2) split, {31-qp, qp}
// two-phase uniform 33 tiles/block, 512 blocks, XCD bh spread, ct-XOR Ps,
// fixed-max base-2 softmax, VALU bf16-rounded l-sum + shfl_xor.
// ---------------------------------------------------------------------------
__global__ __launch_bounds__(512, 4)
void attn_mfma(const unsigned short* __restrict__ qkvb,
               const unsigned short* __restrict__ vt,
               unsigned short* __restrict__ y) {
  const int n = blockIdx.x;
  const int bh = (n & 7) + 8 * ((n >> 3) & 3);  // 4 bh per XCD -> L2-local K/V
  const int qp = n >> 5;                        // 0..15
  const int b = bh >> 4, h = bh & 15;
  const int tid = threadIdx.x;
  const int w = tid >> 6;
  const int lane = tid & 63;
  const int l15 = lane & 15, quad = lane >> 4;
  const int wq = w >> 1, kh2 = w & 1;

  __shared__ __align__(16) char Kb[2 * 8192];       // 16 KB (dbuf)
  __shared__ __align__(16) char Vb[3 * 8192];       // 24 KB (tri-buf)
  __shared__ __align__(16) char PsArena[8 * 2304];  // 18,432 B; Red alias
  __shared__ float Red2[4][16];

  char* psw = PsArena + w * 2304;  // per-wave private P staging (ct-XOR swz)
  const int psrow = l15 * 144;

  const int lr = lane >> 3;
  const int lc = lane & 7;
  const int srcoff = ((lc ^ lr) << 4);
  const char* ksrc = (const char*)qkvb + ((size_t)(b * TT) * C3 + 1024 + h * 64) * 2;
  const char* vsrc = (const char*)vt + ((size_t)(b * HH + h) * DD * TT) * 2;

  const int fro = l15 * 128 + ((quad ^ (l15 & 7)) << 4);
  const int vxor = kh2 << 6;  // key-half select for V fragment reads
  const int pfoff = ((((quad >> 1) + l15) & 3) << 5) + ((quad & 1) << 4);
  const int epoff = l15 * 64 + ((quad ^ (l15 & 3)) << 4);

  for (int phase = 0; phase < 2; ++phase) {
    const int qt = phase ? qp : 31 - qp;   // phase tiles: (32-qp)+(qp+1)=33
    const int nt = qt + 1;                 // 64-key tiles this phase
    const int rmin = qt * 64 + wq * 16;    // wave's min q-row
    const int rmax = rmin + 15;
    const int dk = rmax - kh2 * 32;
    const int jl = (dk >= 0) ? (dk >> 6) : -1;  // wave's last active tile

    if (phase) __syncthreads();  // phase-0 LDS reads fully drained

    // Q fragments: wave's 16 rows (pre-scaled by 0.125*log2e in prep)
    const unsigned short* qrow =
        qkvb + (size_t)(b * TT + rmin + l15) * C3 + h * DD;
    bf16x8 qf0 = *(const bf16x8*)(qrow + quad * 8);
    bf16x8 qf1 = *(const bf16x8*)(qrow + 32 + quad * 8);

    f32x4 O[4];
    float lsum = 0.f;
#pragma unroll
    for (int dt = 0; dt < 4; ++dt) O[dt] = (f32x4){0.f, 0.f, 0.f, 0.f};

    // prologue: stage tile 0 into buf 0 (each wave: 8 K-rows + 8 V-rows)
    async_cp16(ksrc + (size_t)(w * 8 + lr) * (C3 * 2) + srcoff, Kb + w * 1024);
    async_cp16(vsrc + (size_t)(w * 8 + lr) * (TT * 2) + srcoff, Vb + w * 1024);

    int pend = -1;  // tile whose P is staged in Ps, PV not yet done
    for (int j = 0; j < nt; ++j) {
      __syncthreads();  // tile j staged; reads of overwritten bufs done

      if (j + 1 < nt) {
        const int key1 = (j + 1) * 64;
        async_cp16(ksrc + (size_t)(key1 + w * 8 + lr) * (C3 * 2) + srcoff,
                   Kb + ((j + 1) & 1) * 8192 + w * 1024);
        async_cp16(vsrc + (size_t)(w * 8 + lr) * (TT * 2) + key1 * 2 + srcoff,
                   Vb + ((j + 1) % 3) * 8192 + w * 1024);
      }

      const bool act = (j <= jl);
      const bool havep = (pend >= 0);

      // pf read FIRST: latency covered by the K ds_reads + S-MFMAs below.
      bf16x8 pf;
      if (havep) pf = *(const bf16x8*)(psw + psrow + pfoff);

      // ---- S^T = K Q^T - 12 for tile j (32 keys x 16 queries) ----
      f32x4 S[2];
      if (act) {
        const char* Kc = Kb + (j & 1) * 8192;
        const int klo = 64 * j + kh2 * 32;
#pragma unroll
        for (int kt = 0; kt < 2; ++kt) {
          const int ct = kh2 * 2 + kt;
          bf16x8 k0 = *(const bf16x8*)(Kc + ct * 2048 + fro);
          bf16x8 k1 = *(const bf16x8*)(Kc + ct * 2048 + (fro ^ 64));
          f32x4 z = (f32x4){-12.f, -12.f, -12.f, -12.f};
          z = __builtin_amdgcn_mfma_f32_16x16x32_bf16(k0, qf0, z, 0, 0, 0);
          z = __builtin_amdgcn_mfma_f32_16x16x32_bf16(k1, qf1, z, 0, 0, 0);
          S[kt] = z;
        }
        if (klo + 31 > rmin) {  // diagonal overlap: causal mask
#pragma unroll
          for (int kt = 0; kt < 2; ++kt)
#pragma unroll
            for (int r = 0; r < 4; ++r)
              if (klo + kt * 16 + quad * 4 + r > rmin + l15)
                S[kt][r] = -INFINITY;
        }
      }

      // ---- deferred PV of tile pend (overlaps exp2(j) below) ----
      if (havep) {
        const char* Vp = Vb + (pend % 3) * 8192;
        __builtin_amdgcn_s_setprio(1);
#pragma unroll
        for (int dt = 0; dt < 4; ++dt) {
          bf16x8 vf = *(const bf16x8*)(Vp + dt * 2048 + (fro ^ vxor));
          O[dt] = __builtin_amdgcn_mfma_f32_16x16x32_bf16(vf, pf, O[dt], 0, 0, 0);
        }
        __builtin_amdgcn_s_setprio(0);
        pend = -1;
      }

      // ---- exp2 + pack + VALU l-sum + Ps write for tile j ----
      if (act) {
#pragma unroll
        for (int kt = 0; kt < 2; ++kt) {
          u32x2 d;
          d[0] = pack2bf(__builtin_amdgcn_exp2f(S[kt][0]),
                         __builtin_amdgcn_exp2f(S[kt][1]));
          d[1] = pack2bf(__builtin_amdgcn_exp2f(S[kt][2]),
                         __builtin_amdgcn_exp2f(S[kt][3]));
          // l-sum of the bf16-ROUNDED values (r3/r4-verified numerics)
          lsum += __uint_as_float(d[0] << 16) +
                  __uint_as_float(d[0] & 0xffff0000u) +
                  __uint_as_float(d[1] << 16) +
                  __uint_as_float(d[1] & 0xffff0000u);
          *(u32x2*)(psw + psrow + (((kt + l15) & 3) << 5) + quad * 8) = d;
        }
        pend = j;
      }
    }

    // ---- drain final pending PV (tri-buf slot untouched since staging) ----
    if (pend >= 0) {
      bf16x8 pf = *(const bf16x8*)(psw + psrow + pfoff);
      const char* Vp = Vb + (pend % 3) * 8192;
#pragma unroll
      for (int dt = 0; dt < 4; ++dt) {
        bf16x8 vf = *(const bf16x8*)(Vp + dt * 2048 + (fro ^ vxor));
        O[dt] = __builtin_amdgcn_mfma_f32_16x16x32_bf16(vf, pf, O[dt], 0, 0, 0);
      }
    }

    // ---- intra-wave l reduce across quads ----
    lsum += __shfl_xor(lsum, 16, 64);
    lsum += __shfl_xor(lsum, 32, 64);

    // ---- pair-reduction over key-halves: w(kh2=0) += w(kh2=1) ----
    __syncthreads();  // all Ps/K/V reads done; arena becomes Red
    if (kh2) {
      char* rs = PsArena + wq * 4096;
#pragma unroll
      for (int dt = 0; dt < 4; ++dt)
        *(f32x4*)(rs + dt * 1024 + epoff) = O[dt];
      if (quad == 0) Red2[wq][l15] = lsum;
    }
    __syncthreads();
    if (!kh2) {
      const char* rs = PsArena + wq * 4096;
#pragma unroll
      for (int dt = 0; dt < 4; ++dt)
        O[dt] += *(const f32x4*)(rs + dt * 1024 + epoff);
      const float inv = 1.0f / (lsum + Red2[wq][l15]);
      unsigned short* yr =
          y + (size_t)(b * TT + rmin + l15) * CC + h * DD + quad * 4;
#pragma unroll
      for (int dt = 0; dt < 4; ++dt) {
        bf16x4 o = {(short)f2bf(O[dt][0] * inv), (short)f2bf(O[dt][1] * inv),
                    (short)f2bf(O[dt][2] * inv), (short)f2bf(O[dt][3] * inv)};
        *(bf16x4*)(yr + dt * 16) = o;
      }
    }
  }
}

// ---------------------------------------------------------------------------
extern "C" void kernel_launch(void* const* d_in, const int* in_sizes, int n_in,
                              void* d_out, int out_size, void* d_ws,
                              size_t ws_size, hipStream_t stream) {
  const float* x      = (const float*)d_in[0];
  const float* w_attn = (const float*)d_in[1];
  const float* w_proj = (const float*)d_in[2];
  float* out = (float*)d_out;

  unsigned short* xb   = (unsigned short*)d_ws;
  unsigned short* wat  = xb + (size_t)4096 * 1024;
  unsigned short* wpt  = wat + (size_t)3072 * 1024;
  unsigned short* qkvb = wpt + (size_t)1024 * 1024;
  unsigned short* vt   = qkvb + (size_t)4096 * 3072;
  unsigned short* yb   = vt + (size_t)BB * HH * DD * TT;

  dim3 blk(256);

  prep<<<2048, blk, 0, stream>>>(x, w_attn, w_proj, xb, wat, wpt);

  gemm_qkv<<<dim3(C3 / 128, (BB * TT) / 128), blk, 0, stream>>>(
      xb, wat, qkvb, vt);

  attn_mfma<<<dim3(512, 1, 1), dim3(512), 0, stream>>>(qkvb, vt, yb);

  gemm_out<<<dim3(CC / 128, (BB * TT) / 64), blk, 0, stream>>>(yb, wpt, out);
}